// Round 8
// baseline (1385.497 us; speedup 1.0000x reference)
//
#include <hip/hip_runtime.h>
#include <hip/hip_bf16.h>
#include <stdint.h>

#define T_TOK 8192
#define DIM   2048
#define NEXP  8
#define HDIM  1408
#define SHDIM 2816

typedef __attribute__((ext_vector_type(8))) short bfrag;   // 8 x bf16 (4 VGPR)
typedef __attribute__((ext_vector_type(4))) float f32x4;
typedef __attribute__((ext_vector_type(4))) short s16x4;

__device__ __forceinline__ short f2bf(float f) {
    union { float f; uint32_t u; } v; v.f = f;
    return (short)((v.u + 0x8000u) >> 16);   // round-half-up bf16
}
__device__ __forceinline__ float bf2f(short s) {
    union { uint32_t u; float f; } v; v.u = ((uint32_t)(uint16_t)s) << 16;
    return v.f;
}

__device__ __forceinline__ bfrag cvt8(float4 a, float4 b) {
    bfrag r;
    r[0] = f2bf(a.x); r[1] = f2bf(a.y); r[2] = f2bf(a.z); r[3] = f2bf(a.w);
    r[4] = f2bf(b.x); r[5] = f2bf(b.y); r[6] = f2bf(b.z); r[7] = f2bf(b.w);
    return r;
}

__device__ __forceinline__ void gload16(const void* g, void* l) {
    __builtin_amdgcn_global_load_lds(
        (__attribute__((address_space(1))) void*)(g),
        (__attribute__((address_space(3))) void*)(l), 16, 0, 0);
}

#define MFMA16(a, b, c) __builtin_amdgcn_mfma_f32_16x16x32_bf16((a), (b), (c), 0, 0, 0)

// meta: ints [0..7] counts, [8..15] cursor, [16..24] offsets; floats at +32: s_e[8]

__global__ __launch_bounds__(256) void gate_kernel(
    const float* __restrict__ x, const float* __restrict__ gw,
    __hip_bfloat16* __restrict__ xbf,
    int* __restrict__ sel, int* __restrict__ meta, float* __restrict__ s_e)
{
    __shared__ float g[NEXP * DIM];            // 64 KB
    for (int i = threadIdx.x; i < NEXP * DIM; i += 256) g[i] = gw[i];
    __syncthreads();
    const int wid = threadIdx.x >> 6, lane = threadIdx.x & 63;
    for (int it = 0; it < 8; ++it) {
        const int t = blockIdx.x * 32 + wid * 8 + it;
        float acc[NEXP];
#pragma unroll
        for (int e = 0; e < NEXP; ++e) acc[e] = 0.f;
        const float4* xr = (const float4*)(x + (size_t)t * DIM);
        for (int j = 0; j < DIM / 4; j += 64) {
            float4 xv = xr[j + lane];
            s16x4 xv16 = { f2bf(xv.x), f2bf(xv.y), f2bf(xv.z), f2bf(xv.w) };
            *(s16x4*)&xbf[(size_t)t * DIM + (j + lane) * 4] = xv16;
#pragma unroll
            for (int e = 0; e < NEXP; ++e) {
                float4 gv = *(const float4*)&g[e * DIM + (j + lane) * 4];
                acc[e] += xv.x * gv.x + xv.y * gv.y + xv.z * gv.z + xv.w * gv.w;
            }
        }
#pragma unroll
        for (int e = 0; e < NEXP; ++e)
            for (int o = 32; o; o >>= 1) acc[e] += __shfl_xor(acc[e], o);
        if (lane == 0) {
            int e0 = 0; float v0 = acc[0];
#pragma unroll
            for (int e = 1; e < NEXP; ++e) if (acc[e] > v0) { v0 = acc[e]; e0 = e; }
            int e1 = -1; float v1 = -3.4e38f;
#pragma unroll
            for (int e = 0; e < NEXP; ++e) if (e != e0 && acc[e] > v1) { v1 = acc[e]; e1 = e; }
            float p0 = 1.f / (1.f + __expf(v1 - v0));
            float p1 = 1.f - p0;
            sel[2 * t] = e0; sel[2 * t + 1] = e1;
            atomicAdd(&s_e[e0], p0); atomicAdd(&s_e[e1], p1);
            atomicAdd(&meta[e0], 1); atomicAdd(&meta[e1], 1);
        }
    }
}

__global__ void scan_kernel(int* meta) {
    if (threadIdx.x == 0) {
        int acc = 0;
        for (int e = 0; e < NEXP; ++e) {
            meta[16 + e] = acc;
            meta[8 + e]  = acc;
            acc += meta[e];
        }
        meta[24] = acc;
    }
}

__global__ __launch_bounds__(256) void fill_kernel(
    const int* __restrict__ sel, int* __restrict__ meta,
    int* __restrict__ list, int2* __restrict__ slots)
{
    const int t = blockIdx.x * 256 + threadIdx.x;
    int e0 = sel[2 * t], e1 = sel[2 * t + 1];
    int p0 = atomicAdd(&meta[8 + e0], 1); list[p0] = t;
    int p1 = atomicAdd(&meta[8 + e1], 1); list[p1] = t;
    slots[t] = make_int2(p0, p1);
}

// ============ R3-structure GEMMs with fused fp32->bf16 B staging ============
// Per K-tile: {issue B fp32 global loads (t+1) + A global_load_lds (t+1, buf^1);
// ds_read+MFMA (cur); cvt+ds_write B (t+1, buf^1); __syncthreads}.
// LDS layout (verified 0-conflict, R3): for row r, 16B-slot g:
//   byte = r*128 + ((g ^ (r&7)) << 4); A staged via inverse-swizzled source,
//   B written directly at swizzled address (reg-staged => both-sides explicit).

// fused gate+up: act = silu(X@W1^T) * (X@W3^T). BM=256, BN=128, BK=64.
template<int N, bool GATHER>
__global__ __launch_bounds__(512, 2) void up_v8(
    const __hip_bfloat16* __restrict__ X,    // [T,DIM] bf16
    const float* __restrict__ W1,            // [E][N][DIM] fp32
    const float* __restrict__ W3,
    __hip_bfloat16* __restrict__ act,        // [rows][N]
    const int* __restrict__ list,
    const int* __restrict__ meta)
{
    constexpr int K = DIM;
    constexpr int NT = K / 64;
    constexpr int nx = N / 128, ny = T_TOK / 256, nz = GATHER ? NEXP : 1;
    constexpr int nwg = nx * ny * nz, cpx = nwg / 8;
    const int bid = (int)blockIdx.x + nx * ((int)blockIdx.y + ny * (int)blockIdx.z);
    const int virt = (bid & 7) * cpx + (bid >> 3);
    const int xi = virt % nx;
    const int rest = virt / nx;
    const int yi = rest % ny;
    const int e = rest / ny;

    int count, base;
    if (GATHER) {
        count = meta[e]; base = meta[16 + e];
        if (yi * 256 >= count) return;
    } else { count = T_TOK; base = 0; }
    const int m0 = yi * 256, n0 = xi * 128;

    __shared__ alignas(16) short As[2][256 * 64];    // 64 KB
    __shared__ alignas(16) short B1s[2][128 * 64];   // 32 KB
    __shared__ alignas(16) short B3s[2][128 * 64];   // 32 KB

    const int tid = threadIdx.x, wid = tid >> 6, lane = tid & 63;
    const int rlo = lane >> 3;               // row within 8-row chunk
    const int swslot = (lane & 7) ^ rlo;     // pre-swizzled source 16B slot (A)

    const __hip_bfloat16* pA[4];
#pragma unroll
    for (int q = 0; q < 4; ++q) {
        int row = (q * 8 + wid) * 8 + rlo;   // 0..255
        int r = m0 + row; if (r > count - 1) r = count - 1;
        int ga = GATHER ? list[base + r] : r;
        pA[q] = X + (size_t)ga * K + swslot * 8;
    }
    // B staging: thread -> row rb (0..127), quarter sq (0..3) = 16 elems
    const int rb = tid >> 2, sq = tid & 3;
    const float* pB1 = W1 + ((size_t)e * N + n0 + rb) * K + sq * 16;
    const float* pB3 = W3 + ((size_t)e * N + n0 + rb) * K + sq * 16;
    // swizzled LDS byte offsets for slots 2sq, 2sq+1 of row rb
    const int wb0 = rb * 128 + (((2 * sq)     ^ (rb & 7)) << 4);
    const int wb1 = rb * 128 + (((2 * sq + 1) ^ (rb & 7)) << 4);

#define STAGE_A(T, BUF) do { const int k0_ = (T) * 64;                          \
    _Pragma("unroll") for (int q = 0; q < 4; ++q)                               \
        gload16(pA[q] + k0_, &As[BUF][(q * 8 + wid) * 512]); } while (0)

    const int wm = wid >> 2, wn = wid & 3;
    const int l15 = lane & 15, lhi = lane >> 4;

    f32x4 accg[8][2], accu[8][2];
#pragma unroll
    for (int i = 0; i < 8; ++i)
#pragma unroll
        for (int j = 0; j < 2; ++j) { accg[i][j] = 0.f; accu[i][j] = 0.f; }

    // prologue: tile 0
    {
        const float4* s1 = (const float4*)pB1;
        const float4* s3 = (const float4*)pB3;
        float4 a0 = s1[0], a1 = s1[1], a2 = s1[2], a3 = s1[3];
        float4 c0 = s3[0], c1 = s3[1], c2 = s3[2], c3 = s3[3];
        *(bfrag*)((char*)B1s[0] + wb0) = cvt8(a0, a1);
        *(bfrag*)((char*)B1s[0] + wb1) = cvt8(a2, a3);
        *(bfrag*)((char*)B3s[0] + wb0) = cvt8(c0, c1);
        *(bfrag*)((char*)B3s[0] + wb1) = cvt8(c2, c3);
        STAGE_A(0, 0);
    }
    __syncthreads();
    int cur = 0;
#pragma unroll 1
    for (int t = 0; t < NT; ++t) {
        float4 a0, a1, a2, a3, c0, c1, c2, c3;
        const bool pf = (t + 1 < NT);
        if (pf) {
            const float4* s1 = (const float4*)(pB1 + (t + 1) * 64);
            const float4* s3 = (const float4*)(pB3 + (t + 1) * 64);
            a0 = s1[0]; a1 = s1[1]; a2 = s1[2]; a3 = s1[3];
            c0 = s3[0]; c1 = s3[1]; c2 = s3[2]; c3 = s3[3];
            STAGE_A(t + 1, cur ^ 1);
        }
        __builtin_amdgcn_sched_barrier(0);   // pin prefetch issue before reads
        bfrag b1f[2][2], b3f[2][2];
#pragma unroll
        for (int j = 0; j < 2; ++j)
#pragma unroll
            for (int kk = 0; kk < 2; ++kk) {
                int rbr = wn * 32 + j * 16 + l15;
                int c = kk * 4 + lhi;
                int off = rbr * 128 + ((c ^ (rbr & 7)) << 4);
                b1f[j][kk] = *(const bfrag*)((const char*)B1s[cur] + off);
                b3f[j][kk] = *(const bfrag*)((const char*)B3s[cur] + off);
            }
        __builtin_amdgcn_s_setprio(1);
#pragma unroll
        for (int i = 0; i < 8; ++i) {
            int ra = wm * 128 + i * 16 + l15;
            const char* abase = (const char*)As[cur] + ra * 128;
            bfrag f0 = *(const bfrag*)(abase + ((lhi       ^ (ra & 7)) << 4));
            bfrag f1 = *(const bfrag*)(abase + (((4 + lhi) ^ (ra & 7)) << 4));
#pragma unroll
            for (int j = 0; j < 2; ++j) {
                accg[i][j] = MFMA16(f0, b1f[j][0], accg[i][j]);
                accu[i][j] = MFMA16(f0, b3f[j][0], accu[i][j]);
                accg[i][j] = MFMA16(f1, b1f[j][1], accg[i][j]);
                accu[i][j] = MFMA16(f1, b3f[j][1], accu[i][j]);
            }
        }
        __builtin_amdgcn_s_setprio(0);
        if (pf) {
            *(bfrag*)((char*)B1s[cur ^ 1] + wb0) = cvt8(a0, a1);
            *(bfrag*)((char*)B1s[cur ^ 1] + wb1) = cvt8(a2, a3);
            *(bfrag*)((char*)B3s[cur ^ 1] + wb0) = cvt8(c0, c1);
            *(bfrag*)((char*)B3s[cur ^ 1] + wb1) = cvt8(c2, c3);
        }
        __syncthreads();                     // drain: tile t+1 (A gload + B writes) ready
        cur ^= 1;
    }
#undef STAGE_A

#pragma unroll
    for (int i = 0; i < 8; ++i)
#pragma unroll
        for (int r = 0; r < 4; ++r) {
            int m = wm * 128 + i * 16 + lhi * 4 + r;
            if (m0 + m < count) {
#pragma unroll
                for (int j = 0; j < 2; ++j) {
                    float gg = accg[i][j][r];
                    float uu = accu[i][j][r];
                    float a = gg / (1.f + __expf(-gg)) * uu;   // silu(g)*u
                    int n = n0 + wn * 32 + j * 16 + l15;
                    act[(size_t)(base + m0 + m) * N + n] = __float2bfloat16(a);
                }
            }
        }
}

// down: y = A @ W2^T. BM=256, BN=256, BK=64. W2 fp32 staged in-kernel.
// TO_BF16: store unscaled bf16 rows to yscr (expert; combine applies s_e).
// else:    store f32 rows straight to out (shared).
template<int KD, bool TO_BF16>
__global__ __launch_bounds__(512, 2) void down_v8(
    const __hip_bfloat16* __restrict__ A,     // act [rows][KD] bf16
    const float* __restrict__ W2,             // [E][DIM][KD] fp32
    float* __restrict__ out,
    __hip_bfloat16* __restrict__ yscr,
    const int* __restrict__ meta)
{
    constexpr int N = DIM;
    constexpr int NT = KD / 64;
    constexpr int nx = N / 256, ny = T_TOK / 256, nz = TO_BF16 ? NEXP : 1;
    constexpr int nwg = nx * ny * nz, cpx = nwg / 8;
    const int bid = (int)blockIdx.x + nx * ((int)blockIdx.y + ny * (int)blockIdx.z);
    const int virt = (bid & 7) * cpx + (bid >> 3);
    const int xi = virt % nx;
    const int rest = virt / nx;
    const int yi = rest % ny;
    const int e = rest / ny;

    int count, base;
    if (TO_BF16) {
        count = meta[e]; base = meta[16 + e];
        if (yi * 256 >= count) return;
    } else { count = T_TOK; base = 0; }
    const int m0 = yi * 256, n0 = xi * 256;

    __shared__ alignas(16) short As[2][256 * 64];    // 64 KB
    __shared__ alignas(16) short Bs[2][256 * 64];    // 64 KB

    const int tid = threadIdx.x, wid = tid >> 6, lane = tid & 63;
    const int rlo = lane >> 3;
    const int swslot = (lane & 7) ^ rlo;

    const __hip_bfloat16* pA[4];
#pragma unroll
    for (int q = 0; q < 4; ++q) {
        int row = (q * 8 + wid) * 8 + rlo;   // 0..255
        int r = m0 + row; if (r > count - 1) r = count - 1;
        pA[q] = A + (size_t)(base + r) * KD + swslot * 8;
    }
    // B staging: thread -> row rb (0..255), half sq (0..1) = 32 elems
    const int rb = tid >> 1, sq = tid & 1;
    const float* pB = W2 + ((size_t)e * N + n0 + rb) * KD + sq * 32;
    int wbB[4];
#pragma unroll
    for (int s = 0; s < 4; ++s)
        wbB[s] = rb * 128 + (((4 * sq + s) ^ (rb & 7)) << 4);

#define STAGE_A(T, BUF) do { const int k0_ = (T) * 64;                          \
    _Pragma("unroll") for (int q = 0; q < 4; ++q)                               \
        gload16(pA[q] + k0_, &As[BUF][(q * 8 + wid) * 512]); } while (0)

    const int wm = wid >> 2, wn = wid & 3;
    const int l15 = lane & 15, lhi = lane >> 4;

    f32x4 acc[8][4];
#pragma unroll
    for (int i = 0; i < 8; ++i)
#pragma unroll
        for (int j = 0; j < 4; ++j) acc[i][j] = 0.f;

    // prologue
    {
        const float4* s = (const float4*)pB;
#pragma unroll
        for (int h = 0; h < 4; ++h) {
            float4 u0 = s[2 * h], u1 = s[2 * h + 1];
            *(bfrag*)((char*)Bs[0] + wbB[h]) = cvt8(u0, u1);
        }
        STAGE_A(0, 0);
    }
    __syncthreads();
    int cur = 0;
#pragma unroll 1
    for (int t = 0; t < NT; ++t) {
        float4 u[8];
        const bool pf = (t + 1 < NT);
        if (pf) {
            const float4* s = (const float4*)(pB + (t + 1) * 64);
#pragma unroll
            for (int h = 0; h < 8; ++h) u[h] = s[h];
            STAGE_A(t + 1, cur ^ 1);
        }
        __builtin_amdgcn_sched_barrier(0);
        bfrag bf[4][2];
#pragma unroll
        for (int j = 0; j < 4; ++j)
#pragma unroll
            for (int kk = 0; kk < 2; ++kk) {
                int rbr = wn * 64 + j * 16 + l15;
                int c = kk * 4 + lhi;
                bf[j][kk] = *(const bfrag*)((const char*)Bs[cur] + rbr * 128 + ((c ^ (rbr & 7)) << 4));
            }
        __builtin_amdgcn_s_setprio(1);
#pragma unroll
        for (int i = 0; i < 8; ++i) {
            int ra = wm * 128 + i * 16 + l15;
            const char* abase = (const char*)As[cur] + ra * 128;
            bfrag f0 = *(const bfrag*)(abase + ((lhi       ^ (ra & 7)) << 4));
            bfrag f1 = *(const bfrag*)(abase + (((4 + lhi) ^ (ra & 7)) << 4));
#pragma unroll
            for (int j = 0; j < 4; ++j) {
                acc[i][j] = MFMA16(f0, bf[j][0], acc[i][j]);
                acc[i][j] = MFMA16(f1, bf[j][1], acc[i][j]);
            }
        }
        __builtin_amdgcn_s_setprio(0);
        if (pf) {
#pragma unroll
            for (int h = 0; h < 4; ++h)
                *(bfrag*)((char*)Bs[cur ^ 1] + wbB[h]) = cvt8(u[2 * h], u[2 * h + 1]);
        }
        __syncthreads();
        cur ^= 1;
    }
#undef STAGE_A

#pragma unroll
    for (int i = 0; i < 8; ++i)
#pragma unroll
        for (int r = 0; r < 4; ++r) {
            int m = wm * 128 + i * 16 + lhi * 4 + r;
            if (m0 + m < count) {
#pragma unroll
                for (int j = 0; j < 4; ++j) {
                    int n = n0 + wn * 64 + j * 16 + l15;
                    if (TO_BF16)
                        yscr[(size_t)(base + m0 + m) * DIM + n] = __float2bfloat16(acc[i][j][r]);
                    else
                        out[(size_t)(m0 + m) * DIM + n] = acc[i][j][r];
                }
            }
        }
}

// out[t] += s_e[e0]*y[slot0] + s_e[e1]*y[slot1]
__global__ __launch_bounds__(256) void combine_kernel(
    float* __restrict__ out, const __hip_bfloat16* __restrict__ yscr,
    const int* __restrict__ sel, const int2* __restrict__ slots,
    const float* __restrict__ s_e)
{
    const int t = blockIdx.x;
    const int d = threadIdx.x * 8;
    const int2 sl = slots[t];
    const float se0 = s_e[sel[2 * t]];
    const float se1 = s_e[sel[2 * t + 1]];
    bfrag y0 = *(const bfrag*)&yscr[(size_t)sl.x * DIM + d];
    bfrag y1 = *(const bfrag*)&yscr[(size_t)sl.y * DIM + d];
    float4* o = (float4*)(out + (size_t)t * DIM + d);
    float4 o0 = o[0], o1 = o[1];
    o0.x += se0 * bf2f(y0[0]) + se1 * bf2f(y1[0]);
    o0.y += se0 * bf2f(y0[1]) + se1 * bf2f(y1[1]);
    o0.z += se0 * bf2f(y0[2]) + se1 * bf2f(y1[2]);
    o0.w += se0 * bf2f(y0[3]) + se1 * bf2f(y1[3]);
    o1.x += se0 * bf2f(y0[4]) + se1 * bf2f(y1[4]);
    o1.y += se0 * bf2f(y0[5]) + se1 * bf2f(y1[5]);
    o1.z += se0 * bf2f(y0[6]) + se1 * bf2f(y1[6]);
    o1.w += se0 * bf2f(y0[7]) + se1 * bf2f(y1[7]);
    o[0] = o0; o[1] = o1;
}

extern "C" void kernel_launch(void* const* d_in, const int* in_sizes, int n_in,
                              void* d_out, int out_size, void* d_ws, size_t ws_size,
                              hipStream_t stream) {
    const float* x   = (const float*)d_in[0];
    const float* gw  = (const float*)d_in[1];
    const float* w1  = (const float*)d_in[2];
    const float* w3  = (const float*)d_in[3];
    const float* w2  = (const float*)d_in[4];
    const float* sw1 = (const float*)d_in[5];
    const float* sw3 = (const float*)d_in[6];
    const float* sw2 = (const float*)d_in[7];
    float* out = (float*)d_out;

    const size_t SZ_X   = (size_t)T_TOK * DIM * 2;            // 32 MB
    const size_t SZ_ACT = (size_t)2 * T_TOK * HDIM * 2;       // 46.1 MB (== T*SHDIM*2)
    const size_t SZ_Y   = (size_t)2 * T_TOK * DIM * 2;        // 64 MB
    const size_t need = SZ_X + SZ_ACT + SZ_Y
                      + (size_t)6 * T_TOK * sizeof(int) + 512;
    if (need > ws_size) return;

    char* p = (char*)d_ws;
    __hip_bfloat16* xbf  = (__hip_bfloat16*)p; p += SZ_X;
    __hip_bfloat16* act  = (__hip_bfloat16*)p; p += SZ_ACT;
    __hip_bfloat16* yscr = (__hip_bfloat16*)p; p += SZ_Y;
    int*  list  = (int*)p;  p += (size_t)2 * T_TOK * sizeof(int);
    int*  sel   = (int*)p;  p += (size_t)2 * T_TOK * sizeof(int);
    int2* slots = (int2*)p; p += (size_t)2 * T_TOK * sizeof(int);
    int*  meta  = (int*)p;
    float* s_e  = (float*)(meta + 32);

    hipMemsetAsync(meta, 0, 256, stream);
    gate_kernel<<<T_TOK / 32, 256, 0, stream>>>(x, gw, xbf, sel, meta, s_e);
    scan_kernel<<<1, 64, 0, stream>>>(meta);
    fill_kernel<<<T_TOK / 256, 256, 0, stream>>>(sel, meta, list, slots);

    // shared expert first (plain f32 stores init out)
    up_v8<SHDIM, false><<<dim3(SHDIM / 128, T_TOK / 256, 1), 512, 0, stream>>>(
        xbf, sw1, sw3, act, nullptr, meta);
    down_v8<SHDIM, false><<<dim3(DIM / 256, T_TOK / 256, 1), 512, 0, stream>>>(
        act, sw2, out, nullptr, meta);
    // sparse experts: act -> y (bf16, unscaled) -> combine with s_e scales
    up_v8<HDIM, true><<<dim3(HDIM / 128, T_TOK / 256, NEXP), 512, 0, stream>>>(
        xbf, w1, w3, act, list, meta);
    down_v8<HDIM, true><<<dim3(DIM / 256, T_TOK / 256, NEXP), 512, 0, stream>>>(
        act, w2, out, yscr, meta);
    combine_kernel<<<T_TOK, 256, 0, stream>>>(out, yscr, sel, slots, s_e);
}

// Round 9
// 1223.445 us; speedup vs baseline: 1.1325x; 1.1325x over previous
//
#include <hip/hip_runtime.h>
#include <hip/hip_bf16.h>
#include <stdint.h>

#define T_TOK 8192
#define DIM   2048
#define NEXP  8
#define HDIM  1408
#define SHDIM 2816

typedef __attribute__((ext_vector_type(8))) short bfrag;   // 8 x bf16 (4 VGPR)
typedef __attribute__((ext_vector_type(4))) float f32x4;
typedef __attribute__((ext_vector_type(4))) short s16x4;

__device__ __forceinline__ short f2bf(float f) {
    union { float f; uint32_t u; } v; v.f = f;
    return (short)((v.u + 0x8000u) >> 16);   // round-half-up bf16
}
__device__ __forceinline__ float bf2f(short s) {
    union { uint32_t u; float f; } v; v.u = ((uint32_t)(uint16_t)s) << 16;
    return v.f;
}

__device__ __forceinline__ bfrag cvt8(float4 a, float4 b) {
    bfrag r;
    r[0] = f2bf(a.x); r[1] = f2bf(a.y); r[2] = f2bf(a.z); r[3] = f2bf(a.w);
    r[4] = f2bf(b.x); r[5] = f2bf(b.y); r[6] = f2bf(b.z); r[7] = f2bf(b.w);
    return r;
}

__device__ __forceinline__ void gload16(const void* g, void* l) {
    __builtin_amdgcn_global_load_lds(
        (__attribute__((address_space(1))) void*)(g),
        (__attribute__((address_space(3))) void*)(l), 16, 0, 0);
}

#define MFMA16(a, b, c) __builtin_amdgcn_mfma_f32_16x16x32_bf16((a), (b), (c), 0, 0, 0)

// meta: ints [0..7] counts, [8..15] cursor, [16..24] offsets; floats at +32: s_e[8]

__global__ __launch_bounds__(256) void gate_kernel(
    const float* __restrict__ x, const float* __restrict__ gw,
    __hip_bfloat16* __restrict__ xbf,
    int* __restrict__ sel, int* __restrict__ meta, float* __restrict__ s_e)
{
    __shared__ float g[NEXP * DIM];            // 64 KB
    for (int i = threadIdx.x; i < NEXP * DIM; i += 256) g[i] = gw[i];
    __syncthreads();
    const int wid = threadIdx.x >> 6, lane = threadIdx.x & 63;
    for (int it = 0; it < 8; ++it) {
        const int t = blockIdx.x * 32 + wid * 8 + it;
        float acc[NEXP];
#pragma unroll
        for (int e = 0; e < NEXP; ++e) acc[e] = 0.f;
        const float4* xr = (const float4*)(x + (size_t)t * DIM);
        for (int j = 0; j < DIM / 4; j += 64) {
            float4 xv = xr[j + lane];
            s16x4 xv16 = { f2bf(xv.x), f2bf(xv.y), f2bf(xv.z), f2bf(xv.w) };
            *(s16x4*)&xbf[(size_t)t * DIM + (j + lane) * 4] = xv16;
#pragma unroll
            for (int e = 0; e < NEXP; ++e) {
                float4 gv = *(const float4*)&g[e * DIM + (j + lane) * 4];
                acc[e] += xv.x * gv.x + xv.y * gv.y + xv.z * gv.z + xv.w * gv.w;
            }
        }
#pragma unroll
        for (int e = 0; e < NEXP; ++e)
            for (int o = 32; o; o >>= 1) acc[e] += __shfl_xor(acc[e], o);
        if (lane == 0) {
            int e0 = 0; float v0 = acc[0];
#pragma unroll
            for (int e = 1; e < NEXP; ++e) if (acc[e] > v0) { v0 = acc[e]; e0 = e; }
            int e1 = -1; float v1 = -3.4e38f;
#pragma unroll
            for (int e = 0; e < NEXP; ++e) if (e != e0 && acc[e] > v1) { v1 = acc[e]; e1 = e; }
            float p0 = 1.f / (1.f + __expf(v1 - v0));
            float p1 = 1.f - p0;
            sel[2 * t] = e0; sel[2 * t + 1] = e1;
            atomicAdd(&s_e[e0], p0); atomicAdd(&s_e[e1], p1);
            atomicAdd(&meta[e0], 1); atomicAdd(&meta[e1], 1);
        }
    }
}

__global__ void scan_kernel(int* meta) {
    if (threadIdx.x == 0) {
        int acc = 0;
        for (int e = 0; e < NEXP; ++e) {
            meta[16 + e] = acc;
            meta[8 + e]  = acc;
            acc += meta[e];
        }
        meta[24] = acc;
    }
}

__global__ __launch_bounds__(256) void fill_kernel(
    const int* __restrict__ sel, int* __restrict__ meta,
    int* __restrict__ list, int2* __restrict__ slots)
{
    const int t = blockIdx.x * 256 + threadIdx.x;
    int e0 = sel[2 * t], e1 = sel[2 * t + 1];
    int p0 = atomicAdd(&meta[8 + e0], 1); list[p0] = t;
    int p1 = atomicAdd(&meta[8 + e1], 1); list[p1] = t;
    slots[t] = make_int2(p0, p1);
}

// one fused fp32->bf16 conversion for the 6 weight tensors
#define C1 2883584
#define C2 5767168
#define C3 8650752
#define C4 9371648
#define C5 10092544
#define C6 10813440
__global__ __launch_bounds__(256) void cvt6_kernel(
    const float* __restrict__ s0, const float* __restrict__ s1, const float* __restrict__ s2,
    const float* __restrict__ s3, const float* __restrict__ s4, const float* __restrict__ s5,
    __hip_bfloat16* __restrict__ d0, __hip_bfloat16* __restrict__ d1, __hip_bfloat16* __restrict__ d2,
    __hip_bfloat16* __restrict__ d3, __hip_bfloat16* __restrict__ d4, __hip_bfloat16* __restrict__ d5)
{
    const int stride = gridDim.x * 256;
    for (int i = blockIdx.x * 256 + threadIdx.x; i < C6; i += stride) {
        const float* s; __hip_bfloat16* d; int off;
        if      (i < C1) { s = s0; d = d0; off = i; }
        else if (i < C2) { s = s1; d = d1; off = i - C1; }
        else if (i < C3) { s = s2; d = d2; off = i - C2; }
        else if (i < C4) { s = s3; d = d3; off = i - C3; }
        else if (i < C5) { s = s4; d = d4; off = i - C4; }
        else             { s = s5; d = d5; off = i - C5; }
        const float4* p = (const float4*)(s + (size_t)off * 8);
        float4 a = p[0], b = p[1];
        *(bfrag*)(d + (size_t)off * 8) = cvt8(a, b);
    }
}

// ======= single-buffered 256-tile GEMMs (m97 2-barrier loop, 2 blocks/CU) =======
// Per K-tile: {__syncthreads (prior reads done); STAGE(t) via global_load_lds;
// __syncthreads (compiler drains vmcnt); ds_read + 64 MFMA/wave}.
// 64 KB LDS/block -> 2 blocks/CU: the co-resident block's MFMA hides the
// stage drain (m114 implicit overlap — the mechanism behind m97's 874 TF).
// LDS layout (verified 0-conflict): row r, slot g: byte = r*128 + ((g^(r&7))<<4)
// staged linearly with inverse-swizzled global source (rule 21).

// fused gate+up: act = silu(X@W1^T) * (X@W3^T). BM=256, BN=128, BK=64.
template<int N, bool GATHER>
__global__ __launch_bounds__(512, 2) void up_v9(
    const __hip_bfloat16* __restrict__ X,
    const __hip_bfloat16* __restrict__ W1,
    const __hip_bfloat16* __restrict__ W3,
    __hip_bfloat16* __restrict__ act,
    const int* __restrict__ list,
    const int* __restrict__ meta)
{
    constexpr int K = DIM;
    constexpr int NT = K / 64;
    constexpr int nx = N / 128, ny = T_TOK / 256, nz = GATHER ? NEXP : 1;
    constexpr int nwg = nx * ny * nz, cpx = nwg / 8;
    const int bid = (int)blockIdx.x + nx * ((int)blockIdx.y + ny * (int)blockIdx.z);
    const int virt = (bid & 7) * cpx + (bid >> 3);
    const int xi = virt % nx;
    const int rest = virt / nx;
    const int yi = rest % ny;
    const int e = rest / ny;

    int count, base;
    if (GATHER) {
        count = meta[e]; base = meta[16 + e];
        if (yi * 256 >= count) return;
    } else { count = T_TOK; base = 0; }
    const int m0 = yi * 256, n0 = xi * 128;

    __shared__ alignas(16) short As[256 * 64];    // 32 KB
    __shared__ alignas(16) short B1s[128 * 64];   // 16 KB
    __shared__ alignas(16) short B3s[128 * 64];   // 16 KB

    const int tid = threadIdx.x, wid = tid >> 6, lane = tid & 63;
    const int rlo = lane >> 3;               // row within 8-row chunk
    const int swslot = (lane & 7) ^ rlo;     // pre-swizzled source 16B slot

    const __hip_bfloat16* pA[4];
#pragma unroll
    for (int q = 0; q < 4; ++q) {
        int row = (q * 8 + wid) * 8 + rlo;   // 0..255
        int r = m0 + row; if (r > count - 1) r = count - 1;
        int ga = GATHER ? list[base + r] : r;
        pA[q] = X + (size_t)ga * K + swslot * 8;
    }
    const __hip_bfloat16* pB1[2];
    const __hip_bfloat16* pB3[2];
#pragma unroll
    for (int q = 0; q < 2; ++q) {
        int row = (q * 8 + wid) * 8 + rlo;   // 0..127
        pB1[q] = W1 + ((size_t)e * N + n0 + row) * K + swslot * 8;
        pB3[q] = W3 + ((size_t)e * N + n0 + row) * K + swslot * 8;
    }

#define STAGE_UP(T) do { const int k0_ = (T) * 64;                              \
    _Pragma("unroll") for (int q = 0; q < 4; ++q)                               \
        gload16(pA[q] + k0_, &As[(q * 8 + wid) * 512]);                         \
    _Pragma("unroll") for (int q = 0; q < 2; ++q) {                             \
        gload16(pB1[q] + k0_, &B1s[(q * 8 + wid) * 512]);                       \
        gload16(pB3[q] + k0_, &B3s[(q * 8 + wid) * 512]); } } while (0)

    const int wm = wid >> 2, wn = wid & 3;
    const int l15 = lane & 15, lhi = lane >> 4;

    f32x4 accg[8][2], accu[8][2];
#pragma unroll
    for (int i = 0; i < 8; ++i)
#pragma unroll
        for (int j = 0; j < 2; ++j) { accg[i][j] = 0.f; accu[i][j] = 0.f; }

#pragma unroll 1
    for (int t = 0; t < NT; ++t) {
        __syncthreads();                     // prior iter's LDS reads complete
        STAGE_UP(t);
        __syncthreads();                     // vmcnt drained -> tile ready
        bfrag b1f[2][2], b3f[2][2];
#pragma unroll
        for (int j = 0; j < 2; ++j)
#pragma unroll
            for (int kk = 0; kk < 2; ++kk) {
                int rb = wn * 32 + j * 16 + l15;
                int c = kk * 4 + lhi;
                int off = rb * 128 + ((c ^ (rb & 7)) << 4);
                b1f[j][kk] = *(const bfrag*)((const char*)B1s + off);
                b3f[j][kk] = *(const bfrag*)((const char*)B3s + off);
            }
        __builtin_amdgcn_s_setprio(1);
#pragma unroll
        for (int i = 0; i < 8; ++i) {
            int ra = wm * 128 + i * 16 + l15;
            const char* abase = (const char*)As + ra * 128;
            bfrag f0 = *(const bfrag*)(abase + ((lhi       ^ (ra & 7)) << 4));
            bfrag f1 = *(const bfrag*)(abase + (((4 + lhi) ^ (ra & 7)) << 4));
#pragma unroll
            for (int j = 0; j < 2; ++j) {
                accg[i][j] = MFMA16(f0, b1f[j][0], accg[i][j]);
                accu[i][j] = MFMA16(f0, b3f[j][0], accu[i][j]);
                accg[i][j] = MFMA16(f1, b1f[j][1], accg[i][j]);
                accu[i][j] = MFMA16(f1, b3f[j][1], accu[i][j]);
            }
        }
        __builtin_amdgcn_s_setprio(0);
    }
#undef STAGE_UP

#pragma unroll
    for (int i = 0; i < 8; ++i)
#pragma unroll
        for (int r = 0; r < 4; ++r) {
            int m = wm * 128 + i * 16 + lhi * 4 + r;
            if (m0 + m < count) {
#pragma unroll
                for (int j = 0; j < 2; ++j) {
                    float gg = accg[i][j][r];
                    float uu = accu[i][j][r];
                    float a = gg / (1.f + __expf(-gg)) * uu;   // silu(g)*u
                    int n = n0 + wn * 32 + j * 16 + l15;
                    act[(size_t)(base + m0 + m) * N + n] = __float2bfloat16(a);
                }
            }
        }
}

// down: y = A @ W2^T. BM=256, BN=256, BK=64.
// TO_BF16: store unscaled bf16 rows to yscr (expert; combine applies s_e).
// else:    store f32 rows straight to out (shared).
template<int KD, bool TO_BF16>
__global__ __launch_bounds__(512, 2) void down_v9(
    const __hip_bfloat16* __restrict__ A,
    const __hip_bfloat16* __restrict__ W2,
    float* __restrict__ out,
    __hip_bfloat16* __restrict__ yscr,
    const int* __restrict__ meta)
{
    constexpr int N = DIM;
    constexpr int NT = KD / 64;
    constexpr int nx = N / 256, ny = T_TOK / 256, nz = TO_BF16 ? NEXP : 1;
    constexpr int nwg = nx * ny * nz, cpx = nwg / 8;
    const int bid = (int)blockIdx.x + nx * ((int)blockIdx.y + ny * (int)blockIdx.z);
    const int virt = (bid & 7) * cpx + (bid >> 3);
    const int xi = virt % nx;
    const int rest = virt / nx;
    const int yi = rest % ny;
    const int e = rest / ny;

    int count, base;
    if (TO_BF16) {
        count = meta[e]; base = meta[16 + e];
        if (yi * 256 >= count) return;
    } else { count = T_TOK; base = 0; }
    const int m0 = yi * 256, n0 = xi * 256;

    __shared__ alignas(16) short As[256 * 64];    // 32 KB
    __shared__ alignas(16) short Bs[256 * 64];    // 32 KB

    const int tid = threadIdx.x, wid = tid >> 6, lane = tid & 63;
    const int rlo = lane >> 3;
    const int swslot = (lane & 7) ^ rlo;

    const __hip_bfloat16* pA[4];
    const __hip_bfloat16* pB[4];
#pragma unroll
    for (int q = 0; q < 4; ++q) {
        int row = (q * 8 + wid) * 8 + rlo;   // 0..255
        int r = m0 + row; if (r > count - 1) r = count - 1;
        pA[q] = A  + (size_t)(base + r) * KD + swslot * 8;
        pB[q] = W2 + ((size_t)e * N + n0 + row) * KD + swslot * 8;
    }

#define STAGE_DN(T) do { const int k0_ = (T) * 64;                              \
    _Pragma("unroll") for (int q = 0; q < 4; ++q) {                             \
        gload16(pA[q] + k0_, &As[(q * 8 + wid) * 512]);                         \
        gload16(pB[q] + k0_, &Bs[(q * 8 + wid) * 512]); } } while (0)

    const int wm = wid >> 2, wn = wid & 3;
    const int l15 = lane & 15, lhi = lane >> 4;

    f32x4 acc[8][4];
#pragma unroll
    for (int i = 0; i < 8; ++i)
#pragma unroll
        for (int j = 0; j < 4; ++j) acc[i][j] = 0.f;

#pragma unroll 1
    for (int t = 0; t < NT; ++t) {
        __syncthreads();
        STAGE_DN(t);
        __syncthreads();
        bfrag bf[4][2];
#pragma unroll
        for (int j = 0; j < 4; ++j)
#pragma unroll
            for (int kk = 0; kk < 2; ++kk) {
                int rb = wn * 64 + j * 16 + l15;
                int c = kk * 4 + lhi;
                bf[j][kk] = *(const bfrag*)((const char*)Bs + rb * 128 + ((c ^ (rb & 7)) << 4));
            }
        __builtin_amdgcn_s_setprio(1);
#pragma unroll
        for (int i = 0; i < 8; ++i) {
            int ra = wm * 128 + i * 16 + l15;
            const char* abase = (const char*)As + ra * 128;
            bfrag f0 = *(const bfrag*)(abase + ((lhi       ^ (ra & 7)) << 4));
            bfrag f1 = *(const bfrag*)(abase + (((4 + lhi) ^ (ra & 7)) << 4));
#pragma unroll
            for (int j = 0; j < 4; ++j) {
                acc[i][j] = MFMA16(f0, bf[j][0], acc[i][j]);
                acc[i][j] = MFMA16(f1, bf[j][1], acc[i][j]);
            }
        }
        __builtin_amdgcn_s_setprio(0);
    }
#undef STAGE_DN

#pragma unroll
    for (int i = 0; i < 8; ++i)
#pragma unroll
        for (int r = 0; r < 4; ++r) {
            int m = wm * 128 + i * 16 + lhi * 4 + r;
            if (m0 + m < count) {
#pragma unroll
                for (int j = 0; j < 4; ++j) {
                    int n = n0 + wn * 64 + j * 16 + l15;
                    if (TO_BF16)
                        yscr[(size_t)(base + m0 + m) * DIM + n] = __float2bfloat16(acc[i][j][r]);
                    else
                        out[(size_t)(m0 + m) * DIM + n] = acc[i][j][r];
                }
            }
        }
}

// out[t] += s_e[e0]*y[slot0] + s_e[e1]*y[slot1]
__global__ __launch_bounds__(256) void combine_kernel(
    float* __restrict__ out, const __hip_bfloat16* __restrict__ yscr,
    const int* __restrict__ sel, const int2* __restrict__ slots,
    const float* __restrict__ s_e)
{
    const int t = blockIdx.x;
    const int d = threadIdx.x * 8;
    const int2 sl = slots[t];
    const float se0 = s_e[sel[2 * t]];
    const float se1 = s_e[sel[2 * t + 1]];
    bfrag y0 = *(const bfrag*)&yscr[(size_t)sl.x * DIM + d];
    bfrag y1 = *(const bfrag*)&yscr[(size_t)sl.y * DIM + d];
    float4* o = (float4*)(out + (size_t)t * DIM + d);
    float4 o0 = o[0], o1 = o[1];
    o0.x += se0 * bf2f(y0[0]) + se1 * bf2f(y1[0]);
    o0.y += se0 * bf2f(y0[1]) + se1 * bf2f(y1[1]);
    o0.z += se0 * bf2f(y0[2]) + se1 * bf2f(y1[2]);
    o0.w += se0 * bf2f(y0[3]) + se1 * bf2f(y1[3]);
    o1.x += se0 * bf2f(y0[4]) + se1 * bf2f(y1[4]);
    o1.y += se0 * bf2f(y0[5]) + se1 * bf2f(y1[5]);
    o1.z += se0 * bf2f(y0[6]) + se1 * bf2f(y1[6]);
    o1.w += se0 * bf2f(y0[7]) + se1 * bf2f(y1[7]);
    o[0] = o0; o[1] = o1;
}

extern "C" void kernel_launch(void* const* d_in, const int* in_sizes, int n_in,
                              void* d_out, int out_size, void* d_ws, size_t ws_size,
                              hipStream_t stream) {
    const float* x   = (const float*)d_in[0];
    const float* gw  = (const float*)d_in[1];
    const float* w1  = (const float*)d_in[2];
    const float* w3  = (const float*)d_in[3];
    const float* w2  = (const float*)d_in[4];
    const float* sw1 = (const float*)d_in[5];
    const float* sw3 = (const float*)d_in[6];
    const float* sw2 = (const float*)d_in[7];
    float* out = (float*)d_out;

    const size_t SZ_X   = (size_t)T_TOK * DIM * 2;            // 32 MB
    const size_t SZ_W   = (size_t)NEXP * HDIM * DIM * 2;      // 46.1 MB each
    const size_t SZ_SW  = (size_t)SHDIM * DIM * 2;            // 11.5 MB each
    const size_t SZ_ACT = (size_t)2 * T_TOK * HDIM * 2;       // 46.1 MB
    const size_t need = SZ_X + 3 * SZ_W + 3 * SZ_SW + SZ_ACT
                      + (size_t)6 * T_TOK * sizeof(int) + 512;
    if (need > ws_size) return;

    char* p = (char*)d_ws;
    __hip_bfloat16* xbf   = (__hip_bfloat16*)p; p += SZ_X;
    __hip_bfloat16* w1bf  = (__hip_bfloat16*)p; p += SZ_W;
    __hip_bfloat16* w3bf  = (__hip_bfloat16*)p; p += SZ_W;
    __hip_bfloat16* w2bf  = (__hip_bfloat16*)p; p += SZ_W;
    __hip_bfloat16* sw1bf = (__hip_bfloat16*)p; p += SZ_SW;
    __hip_bfloat16* sw3bf = (__hip_bfloat16*)p; p += SZ_SW;
    __hip_bfloat16* sw2bf = (__hip_bfloat16*)p; p += SZ_SW;
    __hip_bfloat16* act   = (__hip_bfloat16*)p; p += SZ_ACT;
    int*  list  = (int*)p;  p += (size_t)2 * T_TOK * sizeof(int);
    int*  sel   = (int*)p;  p += (size_t)2 * T_TOK * sizeof(int);
    int2* slots = (int2*)p; p += (size_t)2 * T_TOK * sizeof(int);
    int*  meta  = (int*)p;
    float* s_e  = (float*)(meta + 32);
    // y scratch (16384 x 2048 bf16 = 64 MB) aliases xbf+w1bf (dead after expert-up)
    __hip_bfloat16* yscr = (__hip_bfloat16*)d_ws;

    hipMemsetAsync(meta, 0, 256, stream);
    gate_kernel<<<T_TOK / 32, 256, 0, stream>>>(x, gw, xbf, sel, meta, s_e);
    scan_kernel<<<1, 64, 0, stream>>>(meta);
    fill_kernel<<<T_TOK / 256, 256, 0, stream>>>(sel, meta, list, slots);

    cvt6_kernel<<<2048, 256, 0, stream>>>(w1, w3, w2, sw1, sw3, sw2,
                                          w1bf, w3bf, w2bf, sw1bf, sw3bf, sw2bf);

    // shared expert first (plain f32 stores init out)
    up_v9<SHDIM, false><<<dim3(SHDIM / 128, T_TOK / 256, 1), 512, 0, stream>>>(
        xbf, sw1bf, sw3bf, act, nullptr, meta);
    down_v9<SHDIM, false><<<dim3(DIM / 256, T_TOK / 256, 1), 512, 0, stream>>>(
        act, sw2bf, out, nullptr, meta);
    // sparse experts: act -> y (bf16, unscaled) -> combine with s_e scales
    up_v9<HDIM, true><<<dim3(HDIM / 128, T_TOK / 256, NEXP), 512, 0, stream>>>(
        xbf, w1bf, w3bf, act, list, meta);
    down_v9<HDIM, true><<<dim3(DIM / 256, T_TOK / 256, NEXP), 512, 0, stream>>>(
        act, w2bf, out, yscr, meta);
    combine_kernel<<<T_TOK, 256, 0, stream>>>(out, yscr, sel, slots, s_e);
}